// Round 19
// baseline (192.423 us; speedup 1.0000x reference)
//
#include <hip/hip_runtime.h>

#define C_LENX 2048
#define Q_LENX 512
#define BATCH  32
#define HDIM   256
#define BH     8192
#define CBLK   128            // 2 c-sets x 4 waves x 16 rows
#define QBLK   32
#define NQT    16
#define TILE_BYTES 32768      // qf 16K (fp16[32][256], swz) + qt 16K (V^T chunks)
#define OFF_QT 16384

typedef __attribute__((ext_vector_type(8))) _Float16 f16x8;
typedef __attribute__((ext_vector_type(4))) _Float16 f16x4;
typedef __attribute__((ext_vector_type(4))) float f32x4;

__device__ __forceinline__ unsigned short f2h_bits(float x) {
    union { _Float16 h; unsigned short u; } cv;
    cv.h = (_Float16)x;                     // RTNE
    return cv.u;
}

// ---------------- prep: fp32 Q -> fp16 blob (unchanged from R18) ----------------
// qf: row q (512B); 16B chunk c at byte q*512 + 16*(c ^ (q&7))     [holds Q[q][8c..8c+7]]
// qt: chunk (h*4 + g) at byte OFF_QT + chunk*16 = V^T[h][q=g*8..g*8+7]  (K=32 A-frag)
__global__ __launch_bounds__(256)
void q_prep(const float* __restrict__ question, unsigned char* __restrict__ blob)
{
    __shared__ unsigned short sHf[QBLK][264];
    const int tid = threadIdx.x;
    const int b  = blockIdx.x >> 4;
    const int t  = blockIdx.x & 15;
    const float* qbase = question + (size_t)(t * QBLK) * BH + b * HDIM;
    unsigned char* tb = blob + (size_t)(b * NQT + t) * TILE_BYTES;

    #pragma unroll
    for (int i = 0; i < 8; ++i) {
        int e  = tid + i * 256;          // float4 cell 0..2047
        int qr = e >> 6;                 // 0..31
        int h4 = (e & 63) << 2;          // 0..252
        float4 x = *reinterpret_cast<const float4*>(qbase + (size_t)qr * BH + h4);
        ushort4 hv;
        hv.x = f2h_bits(x.x); hv.y = f2h_bits(x.y);
        hv.z = f2h_bits(x.z); hv.w = f2h_bits(x.w);
        *reinterpret_cast<ushort4*>(&sHf[qr][h4]) = hv;
        int c = h4 >> 3;                 // 16B chunk within row
        *reinterpret_cast<ushort4*>(tb + qr * 512 + ((c ^ (qr & 7)) << 4) + ((h4 & 7) << 1)) = hv;
    }
    __syncthreads();
    #pragma unroll
    for (int i = 0; i < 4; ++i) {
        int e  = tid + i * 256;          // chunk 0..1023
        int h  = e >> 2;                 // 0..255
        int g  = e & 3;                  // q-octet
        int q0 = g * 8;
        ushort4 a, bv;
        a.x  = sHf[q0 + 0][h]; a.y  = sHf[q0 + 1][h];
        a.z  = sHf[q0 + 2][h]; a.w  = sHf[q0 + 3][h];
        bv.x = sHf[q0 + 4][h]; bv.y = sHf[q0 + 5][h];
        bv.z = sHf[q0 + 6][h]; bv.w = sHf[q0 + 7][h];
        *reinterpret_cast<ushort4*>(tb + OFF_QT + e * 16)     = a;
        *reinterpret_cast<ushort4*>(tb + OFF_QT + e * 16 + 8) = bv;
    }
}

// ---- main: R18 minus LDS staging — barrier-free free-run; reads via L1/L2 ----
__global__ __launch_bounds__(256, 2)
void s2s_attn(const float* __restrict__ content,
              const unsigned char* __restrict__ blob,
              const int*   __restrict__ qmask,
              float*       __restrict__ out)
{
    __shared__ __attribute__((aligned(16))) unsigned short sP[2][4][16][40]; // pitch 80B

    const int tid  = threadIdx.x;
    const int wid  = tid >> 6;
    const int lane = tid & 63;
    const int lr   = lane & 15;
    const int lg   = lane >> 4;

    // XCD-aware swizzle: 512 blocks, 64/XCD -> each XCD owns 4 complete batches
    const int lin = (blockIdx.x & 7) * 64 + (blockIdx.x >> 3);
    const int ct = lin & 15;             // 16 c-tiles per batch
    const int b  = lin >> 4;
    const int c0 = ct * CBLK;

    // hoist mask: one ballot word per q-tile (wave-uniform -> SGPRs)
    unsigned mwv[NQT];
    #pragma unroll
    for (int t = 0; t < NQT; ++t)
        mwv[t] = (unsigned)__ballot(qmask[b * Q_LENX + t * QBLK + (lane & 31)] != 0);

    // content preload: two c-sets of 16 rows each (K=32 A/B layout: row=lr, k=lg*8)
    f16x8 chi0[8], chi1[8];
    {
        const float* cb0 = content + (size_t)(c0 + wid*16 + lr) * BH + b*HDIM + lg*8;
        const float* cb1 = cb0 + (size_t)64 * BH;
        #pragma unroll
        for (int kc = 0; kc < 8; ++kc) {
            float4 x0 = *reinterpret_cast<const float4*>(cb0 + kc*32);
            float4 x1 = *reinterpret_cast<const float4*>(cb0 + kc*32 + 4);
            float4 y0 = *reinterpret_cast<const float4*>(cb1 + kc*32);
            float4 y1 = *reinterpret_cast<const float4*>(cb1 + kc*32 + 4);
            float xs[8] = {x0.x,x0.y,x0.z,x0.w,x1.x,x1.y,x1.z,x1.w};
            float ys[8] = {y0.x,y0.y,y0.z,y0.w,y1.x,y1.y,y1.z,y1.w};
            #pragma unroll
            for (int j = 0; j < 8; ++j) {
                chi0[kc][j] = (_Float16)xs[j];
                chi1[kc][j] = (_Float16)ys[j];
            }
        }
    }

    // acc[s][n]: O^T fragment — lane holds O[c = c0 + s*64 + wid*16 + lr][h = n*16+lg*4+r]
    f32x4 acc0[16], acc1[16];
    #pragma unroll
    for (int n = 0; n < 16; ++n) {
        f32x4 z = {0.f,0.f,0.f,0.f};
        acc0[n] = z; acc1[n] = z;
    }
    float m_run0 = -INFINITY, m_run1 = -INFINITY;
    float l_run0 = 0.f, l_run1 = 0.f;   // per-lane PARTIAL sums; reduced at epilogue

    const unsigned swz = (unsigned)(lr & 7);   // (16+lr)&7 == lr&7

    for (int t = 0; t < NQT; ++t) {
        const unsigned char* qf = blob + (size_t)(b * NQT + t) * TILE_BYTES;
        const unsigned char* qt = qf + OFF_QT;
        const unsigned mw = mwv[t];

        // ---- prefetch all 16 qf fragments (global, L1/L2-served) ----
        f16x8 qfr[16];
        #pragma unroll
        for (int kc = 0; kc < 8; ++kc) {
            unsigned off = (unsigned)((kc*4 + lg) ^ swz) << 4;
            qfr[2*kc]   = *reinterpret_cast<const f16x8*>(qf + lr*512 + off);
            qfr[2*kc+1] = *reinterpret_cast<const f16x8*>(qf + (16+lr)*512 + off);
        }
        // ---- vt first half: issued now, consumed after softmax ----
        f16x8 vt0[8];
        #pragma unroll
        for (int n = 0; n < 8; ++n)
            vt0[n] = *reinterpret_cast<const f16x8*>(qt + (((n*16 + lr)*4 + lg) << 4));

        // ---- QK^T both sets: 4 chains (2 per set), depth 8 ----
        f32x4 zz = {0.f,0.f,0.f,0.f};
        f32x4 sA0=zz, sB0=zz, sA1=zz, sB1=zz;
        __builtin_amdgcn_s_setprio(1);
        #pragma unroll
        for (int kc = 0; kc < 8; ++kc) {
            sA0 = __builtin_amdgcn_mfma_f32_16x16x32_f16(qfr[2*kc],   chi0[kc], sA0, 0, 0, 0);
            sB0 = __builtin_amdgcn_mfma_f32_16x16x32_f16(qfr[2*kc+1], chi0[kc], sB0, 0, 0, 0);
            sA1 = __builtin_amdgcn_mfma_f32_16x16x32_f16(qfr[2*kc],   chi1[kc], sA1, 0, 0, 0);
            sB1 = __builtin_amdgcn_mfma_f32_16x16x32_f16(qfr[2*kc+1], chi1[kc], sB1, 0, 0, 0);
        }
        __builtin_amdgcn_s_setprio(0);
        // sA*: S^T rows q=lg*4+r, col c=lr;  sB*: rows q=16+lg*4+r

        // ---- softmax both sets; uniform-mask fast path (mw is SGPR) ----
        float p0v[8], p1v[8];
        float tm0 = -INFINITY, tm1 = -INFINITY;
        if (mw == 0xffffffffu) {
            #pragma unroll
            for (int r = 0; r < 4; ++r) {
                p0v[r] = sA0[r]; p0v[4+r] = sB0[r];
                p1v[r] = sA1[r]; p1v[4+r] = sB1[r];
                tm0 = fmaxf(tm0, fmaxf(sA0[r], sB0[r]));
                tm1 = fmaxf(tm1, fmaxf(sA1[r], sB1[r]));
            }
        } else {
            #pragma unroll
            for (int r = 0; r < 4; ++r) {
                bool okA = (mw >> (lg*4 + r)) & 1u;
                bool okB = (mw >> (16 + lg*4 + r)) & 1u;
                float a0 = okA ? sA0[r] : -INFINITY;
                float b0v = okB ? sB0[r] : -INFINITY;
                float a1 = okA ? sA1[r] : -INFINITY;
                float b1v = okB ? sB1[r] : -INFINITY;
                p0v[r] = a0; p0v[4+r] = b0v;
                p1v[r] = a1; p1v[4+r] = b1v;
                tm0 = fmaxf(tm0, fmaxf(a0, b0v));
                tm1 = fmaxf(tm1, fmaxf(a1, b1v));
            }
        }
        tm0 = fmaxf(tm0, __shfl_xor(tm0, 16, 64));
        tm0 = fmaxf(tm0, __shfl_xor(tm0, 32, 64));
        tm1 = fmaxf(tm1, __shfl_xor(tm1, 16, 64));
        tm1 = fmaxf(tm1, __shfl_xor(tm1, 32, 64));

        if (__ballot((tm0 > m_run0 + 4.0f) || (tm1 > m_run1 + 4.0f))) {   // T13 defer-max
            float mn0 = fmaxf(m_run0, tm0);
            float mn1 = fmaxf(m_run1, tm1);
            float sc0 = 1.f, sc1 = 1.f;
            if (mn0 != -INFINITY) { sc0 = __expf(m_run0 - mn0); m_run0 = mn0; }
            if (mn1 != -INFINITY) { sc1 = __expf(m_run1 - mn1); m_run1 = mn1; }
            l_run0 *= sc0; l_run1 *= sc1;
            #pragma unroll
            for (int n = 0; n < 16; ++n) {
                acc0[n] *= sc0;
                acc1[n] *= sc1;
            }
        }

        _Float16 ph0[8], ph1[8];
        {
            float ps0 = 0.f, ps1 = 0.f;
            if (m_run0 == -INFINITY) {
                #pragma unroll
                for (int i = 0; i < 8; ++i) ph0[i] = (_Float16)0.f;
            } else {
                #pragma unroll
                for (int i = 0; i < 8; ++i) {
                    float e = __expf(p0v[i] - m_run0);
                    ph0[i] = (_Float16)e;
                    ps0 += (float)ph0[i];          // sum ROUNDED weights (partial)
                }
            }
            if (m_run1 == -INFINITY) {
                #pragma unroll
                for (int i = 0; i < 8; ++i) ph1[i] = (_Float16)0.f;
            } else {
                #pragma unroll
                for (int i = 0; i < 8; ++i) {
                    float e = __expf(p1v[i] - m_run1);
                    ph1[i] = (_Float16)e;
                    ps1 += (float)ph1[i];
                }
            }
            l_run0 += ps0;   // per-lane partial; cross-lane reduce deferred to epilogue
            l_run1 += ps1;
        }

        // ---- publish P to per-wave LDS (pitch-40 rows), read back K=32 B-frags ----
        {
            f16x4 w00 = {ph0[0], ph0[1], ph0[2], ph0[3]};
            f16x4 w01 = {ph0[4], ph0[5], ph0[6], ph0[7]};
            f16x4 w10 = {ph1[0], ph1[1], ph1[2], ph1[3]};
            f16x4 w11 = {ph1[4], ph1[5], ph1[6], ph1[7]};
            *reinterpret_cast<f16x4*>(&sP[0][wid][lr][lg*4])      = w00;
            *reinterpret_cast<f16x4*>(&sP[0][wid][lr][16 + lg*4]) = w01;
            *reinterpret_cast<f16x4*>(&sP[1][wid][lr][lg*4])      = w10;
            *reinterpret_cast<f16x4*>(&sP[1][wid][lr][16 + lg*4]) = w11;
        }
        asm volatile("s_waitcnt lgkmcnt(0)" ::: "memory");   // intra-wave LDS visibility
        __builtin_amdgcn_sched_barrier(0);
        f16x8 pf0 = *reinterpret_cast<const f16x8*>(&sP[0][wid][lr][lg*8]);
        f16x8 pf1 = *reinterpret_cast<const f16x8*>(&sP[1][wid][lr][lg*8]);

        // ---- vt second half: overlaps first PV half ----
        f16x8 vt1[8];
        #pragma unroll
        for (int n = 0; n < 8; ++n)
            vt1[n] = *reinterpret_cast<const f16x8*>(qt + ((((n+8)*16 + lr)*4 + lg) << 4));

        // ---- PV both sets at K=32: O^T[h][c] += V^T[h][q] * P^T[q][c]; 32 MFMAs ----
        __builtin_amdgcn_s_setprio(1);
        #pragma unroll
        for (int n = 0; n < 8; ++n) {
            acc0[n] = __builtin_amdgcn_mfma_f32_16x16x32_f16(vt0[n], pf0, acc0[n], 0, 0, 0);
            acc1[n] = __builtin_amdgcn_mfma_f32_16x16x32_f16(vt0[n], pf1, acc1[n], 0, 0, 0);
        }
        #pragma unroll
        for (int n = 0; n < 8; ++n) {
            acc0[8+n] = __builtin_amdgcn_mfma_f32_16x16x32_f16(vt1[n], pf0, acc0[8+n], 0, 0, 0);
            acc1[8+n] = __builtin_amdgcn_mfma_f32_16x16x32_f16(vt1[n], pf1, acc1[8+n], 0, 0, 0);
        }
        __builtin_amdgcn_s_setprio(0);
        // no barrier: waves free-run to the next tile
    }

    // ---- epilogue: reduce partial l across the 4 row-group lanes, then store ----
    l_run0 += __shfl_xor(l_run0, 16, 64);
    l_run0 += __shfl_xor(l_run0, 32, 64);
    l_run1 += __shfl_xor(l_run1, 16, 64);
    l_run1 += __shfl_xor(l_run1, 32, 64);
    float rinv0 = 1.f / l_run0;
    float rinv1 = 1.f / l_run1;
    float* orow0 = out + (size_t)(c0 + wid*16 + lr) * BH + b*HDIM;
    float* orow1 = orow0 + (size_t)64 * BH;
    #pragma unroll
    for (int n = 0; n < 16; ++n) {
        f32x4 v0 = acc0[n] * rinv0;
        f32x4 v1 = acc1[n] * rinv1;
        *reinterpret_cast<f32x4*>(orow0 + n*16 + lg*4) = v0;
        *reinterpret_cast<f32x4*>(orow1 + n*16 + lg*4) = v1;
    }
}

extern "C" void kernel_launch(void* const* d_in, const int* in_sizes, int n_in,
                              void* d_out, int out_size, void* d_ws, size_t ws_size,
                              hipStream_t stream) {
    const float* content  = (const float*)d_in[0];
    const float* question = (const float*)d_in[1];
    const int*   mask     = (const int*)d_in[2];
    float*       out      = (float*)d_out;

    unsigned char* blob = (unsigned char*)d_ws;   // 512 tiles * 32KB = 16 MB

    q_prep<<<BATCH * NQT, 256, 0, stream>>>(question, blob);
    s2s_attn<<<C_LENX / CBLK * BATCH, 256, 0, stream>>>(content, blob, mask, out);
}

// Round 20
// 109.641 us; speedup vs baseline: 1.7550x; 1.7550x over previous
//
#include <hip/hip_runtime.h>

#define C_LENX 2048
#define Q_LENX 512
#define BATCH  32
#define HDIM   256
#define BH     8192
#define CBLK   128            // 2 c-sets x 4 waves x 16 rows
#define QBLK   32
#define NQT    16
#define TILE_BYTES 32768      // qf 16K (fp16[32][256], swz) + qt 16K (V^T chunks, pi-order)
#define OFF_QT 16384

typedef __attribute__((ext_vector_type(8))) _Float16 f16x8;
typedef __attribute__((ext_vector_type(4))) float f32x4;

__device__ __forceinline__ unsigned short f2h_bits(float x) {
    union { _Float16 h; unsigned short u; } cv;
    cv.h = (_Float16)x;                     // RTNE
    return cv.u;
}

// async global->LDS, 16B per lane, wave-uniform LDS base + lane*16
__device__ __forceinline__ void stage16(const void* gsrc, void* ldst) {
    __builtin_amdgcn_global_load_lds(
        (const __attribute__((address_space(1))) unsigned int*)gsrc,
        (__attribute__((address_space(3))) unsigned int*)ldst, 16, 0, 0);
}

// ---------------- prep: fp32 Q -> fp16 blob ----------------
// qf: row q (512B); 16B chunk c at byte q*512 + 16*(c ^ (q&7))     [holds Q[q][8c..8c+7]]
// qt: chunk (h*4+g), PI-PERMUTED q-octet: { Q[4g..4g+3][h], Q[16+4g..16+4g+3][h] }
//     — matches the in-register P layout of lane group g, so PV needs no P shuffle.
__global__ __launch_bounds__(256)
void q_prep(const float* __restrict__ question, unsigned char* __restrict__ blob)
{
    __shared__ unsigned short sHf[QBLK][264];
    const int tid = threadIdx.x;
    const int b  = blockIdx.x >> 4;
    const int t  = blockIdx.x & 15;
    const float* qbase = question + (size_t)(t * QBLK) * BH + b * HDIM;
    unsigned char* tb = blob + (size_t)(b * NQT + t) * TILE_BYTES;

    #pragma unroll
    for (int i = 0; i < 8; ++i) {
        int e  = tid + i * 256;          // float4 cell 0..2047
        int qr = e >> 6;                 // 0..31
        int h4 = (e & 63) << 2;          // 0..252
        float4 x = *reinterpret_cast<const float4*>(qbase + (size_t)qr * BH + h4);
        ushort4 hv;
        hv.x = f2h_bits(x.x); hv.y = f2h_bits(x.y);
        hv.z = f2h_bits(x.z); hv.w = f2h_bits(x.w);
        *reinterpret_cast<ushort4*>(&sHf[qr][h4]) = hv;
        int c = h4 >> 3;                 // 16B chunk within row
        *reinterpret_cast<ushort4*>(tb + qr * 512 + ((c ^ (qr & 7)) << 4) + ((h4 & 7) << 1)) = hv;
    }
    __syncthreads();
    #pragma unroll
    for (int i = 0; i < 4; ++i) {
        int e  = tid + i * 256;          // chunk 0..1023
        int h  = e >> 2;                 // 0..255
        int g  = e & 3;                  // lane-group
        int q0 = g * 4;
        ushort4 a, bv;
        a.x  = sHf[q0 + 0][h];      a.y  = sHf[q0 + 1][h];
        a.z  = sHf[q0 + 2][h];      a.w  = sHf[q0 + 3][h];
        bv.x = sHf[16 + q0 + 0][h]; bv.y = sHf[16 + q0 + 1][h];
        bv.z = sHf[16 + q0 + 2][h]; bv.w = sHf[16 + q0 + 3][h];
        *reinterpret_cast<ushort4*>(tb + OFF_QT + e * 16)     = a;
        *reinterpret_cast<ushort4*>(tb + OFF_QT + e * 16 + 8) = bv;
    }
}

// ---- main: R18 with the sP LDS roundtrip dissolved via pi-permuted K-axis ----
__global__ __launch_bounds__(256, 2)
void s2s_attn(const float* __restrict__ content,
              const unsigned char* __restrict__ blob,
              const int*   __restrict__ qmask,
              float*       __restrict__ out)
{
    __shared__ __attribute__((aligned(16))) unsigned char sBuf[2 * TILE_BYTES];

    const int tid  = threadIdx.x;
    const int wid  = tid >> 6;
    const int lane = tid & 63;
    const int lr   = lane & 15;
    const int lg   = lane >> 4;

    // XCD-aware swizzle: 512 blocks, 64/XCD -> each XCD owns 4 complete batches
    const int lin = (blockIdx.x & 7) * 64 + (blockIdx.x >> 3);
    const int ct = lin & 15;             // 16 c-tiles per batch
    const int b  = lin >> 4;
    const int c0 = ct * CBLK;

    // prologue: DMA tile 0 into buffer 0 (32 segs of 1KB; 8 per wave)
    {
        const unsigned char* tb0 = blob + (size_t)(b * NQT) * TILE_BYTES;
        #pragma unroll
        for (int j = 0; j < 8; ++j) {
            int seg = wid * 8 + j;
            stage16(tb0 + seg * 1024 + lane * 16, sBuf + seg * 1024);
        }
    }

    // hoist mask: one ballot word per q-tile (wave-uniform -> SGPRs)
    unsigned mwv[NQT];
    #pragma unroll
    for (int t = 0; t < NQT; ++t)
        mwv[t] = (unsigned)__ballot(qmask[b * Q_LENX + t * QBLK + (lane & 31)] != 0);

    // content preload: two c-sets of 16 rows each (K=32 A/B layout: row=lr, k=lg*8)
    f16x8 chi0[8], chi1[8];
    {
        const float* cb0 = content + (size_t)(c0 + wid*16 + lr) * BH + b*HDIM + lg*8;
        const float* cb1 = cb0 + (size_t)64 * BH;
        #pragma unroll
        for (int kc = 0; kc < 8; ++kc) {
            float4 x0 = *reinterpret_cast<const float4*>(cb0 + kc*32);
            float4 x1 = *reinterpret_cast<const float4*>(cb0 + kc*32 + 4);
            float4 y0 = *reinterpret_cast<const float4*>(cb1 + kc*32);
            float4 y1 = *reinterpret_cast<const float4*>(cb1 + kc*32 + 4);
            float xs[8] = {x0.x,x0.y,x0.z,x0.w,x1.x,x1.y,x1.z,x1.w};
            float ys[8] = {y0.x,y0.y,y0.z,y0.w,y1.x,y1.y,y1.z,y1.w};
            #pragma unroll
            for (int j = 0; j < 8; ++j) {
                chi0[kc][j] = (_Float16)xs[j];
                chi1[kc][j] = (_Float16)ys[j];
            }
        }
    }

    // acc[s][n]: O^T fragment — lane holds O[c = c0 + s*64 + wid*16 + lr][h = n*16+lg*4+r]
    f32x4 acc0[16], acc1[16];
    #pragma unroll
    for (int n = 0; n < 16; ++n) {
        f32x4 z = {0.f,0.f,0.f,0.f};
        acc0[n] = z; acc1[n] = z;
    }
    float m_run0 = -INFINITY, m_run1 = -INFINITY;
    float l_run0 = 0.f, l_run1 = 0.f;   // per-lane PARTIAL sums; reduced at epilogue

    __syncthreads();           // tile 0 DMA drained + visible

    for (int t = 0; t < NQT; ++t) {
        const unsigned char* qf = sBuf + (t & 1) * TILE_BYTES;
        const unsigned char* qt = qf + OFF_QT;

        // T3 2-phase: issue next tile's DMA into the other buffer, compute, one barrier
        if (t + 1 < NQT) {
            const unsigned char* tbn = blob + (size_t)(b * NQT + t + 1) * TILE_BYTES;
            unsigned char* db = sBuf + ((t + 1) & 1) * TILE_BYTES;
            #pragma unroll
            for (int j = 0; j < 8; ++j) {
                int seg = wid * 8 + j;
                stage16(tbn + seg * 1024 + lane * 16, db + seg * 1024);
            }
        }
        const unsigned mw = mwv[t];

        // ---- QK^T both sets: shared qf reads; 4 chains (2 per set), depth 8 ----
        f32x4 zz = {0.f,0.f,0.f,0.f};
        f32x4 sA0=zz, sB0=zz, sA1=zz, sB1=zz;
        const unsigned swz = (unsigned)(lr & 7);   // (16+lr)&7 == lr&7
        __builtin_amdgcn_s_setprio(1);
        #pragma unroll
        for (int kc = 0; kc < 8; ++kc) {
            unsigned off = (unsigned)((kc*4 + lg) ^ swz) << 4;
            f16x8 qa = *reinterpret_cast<const f16x8*>(qf + lr*512 + off);
            f16x8 qb = *reinterpret_cast<const f16x8*>(qf + (16+lr)*512 + off);
            sA0 = __builtin_amdgcn_mfma_f32_16x16x32_f16(qa, chi0[kc], sA0, 0, 0, 0);
            sB0 = __builtin_amdgcn_mfma_f32_16x16x32_f16(qb, chi0[kc], sB0, 0, 0, 0);
            sA1 = __builtin_amdgcn_mfma_f32_16x16x32_f16(qa, chi1[kc], sA1, 0, 0, 0);
            sB1 = __builtin_amdgcn_mfma_f32_16x16x32_f16(qb, chi1[kc], sB1, 0, 0, 0);
        }
        __builtin_amdgcn_s_setprio(0);
        // sA*: S^T rows q=lg*4+r, col c=lr;  sB*: rows q=16+lg*4+r

        // ---- softmax both sets; uniform-mask fast path (mw is SGPR) ----
        float p0v[8], p1v[8];
        float tm0 = -INFINITY, tm1 = -INFINITY;
        if (mw == 0xffffffffu) {
            #pragma unroll
            for (int r = 0; r < 4; ++r) {
                p0v[r] = sA0[r]; p0v[4+r] = sB0[r];
                p1v[r] = sA1[r]; p1v[4+r] = sB1[r];
                tm0 = fmaxf(tm0, fmaxf(sA0[r], sB0[r]));
                tm1 = fmaxf(tm1, fmaxf(sA1[r], sB1[r]));
            }
        } else {
            #pragma unroll
            for (int r = 0; r < 4; ++r) {
                bool okA = (mw >> (lg*4 + r)) & 1u;
                bool okB = (mw >> (16 + lg*4 + r)) & 1u;
                float a0 = okA ? sA0[r] : -INFINITY;
                float b0v = okB ? sB0[r] : -INFINITY;
                float a1 = okA ? sA1[r] : -INFINITY;
                float b1v = okB ? sB1[r] : -INFINITY;
                p0v[r] = a0; p0v[4+r] = b0v;
                p1v[r] = a1; p1v[4+r] = b1v;
                tm0 = fmaxf(tm0, fmaxf(a0, b0v));
                tm1 = fmaxf(tm1, fmaxf(a1, b1v));
            }
        }
        tm0 = fmaxf(tm0, __shfl_xor(tm0, 16, 64));
        tm0 = fmaxf(tm0, __shfl_xor(tm0, 32, 64));
        tm1 = fmaxf(tm1, __shfl_xor(tm1, 16, 64));
        tm1 = fmaxf(tm1, __shfl_xor(tm1, 32, 64));

        if (__ballot((tm0 > m_run0 + 4.0f) || (tm1 > m_run1 + 4.0f))) {   // T13 defer-max
            float mn0 = fmaxf(m_run0, tm0);
            float mn1 = fmaxf(m_run1, tm1);
            float sc0 = 1.f, sc1 = 1.f;
            if (mn0 != -INFINITY) { sc0 = __expf(m_run0 - mn0); m_run0 = mn0; }
            if (mn1 != -INFINITY) { sc1 = __expf(m_run1 - mn1); m_run1 = mn1; }
            l_run0 *= sc0; l_run1 *= sc1;
            #pragma unroll
            for (int n = 0; n < 16; ++n) {
                acc0[n] *= sc0;
                acc1[n] *= sc1;
            }
        }

        // ---- vt loads (pi-permuted V^T chunks): issue now, overlap the exp block ----
        f16x8 vt0[8], vt1[8];
        #pragma unroll
        for (int n = 0; n < 8; ++n) {
            vt0[n] = *reinterpret_cast<const f16x8*>(qt + (((n*16 + lr)*4 + lg) << 4));
            vt1[n] = *reinterpret_cast<const f16x8*>(qt + ((((n+8)*16 + lr)*4 + lg) << 4));
        }

        // ---- exp + partial sums; P stays IN REGISTERS (pi-order == B-frag order) ----
        _Float16 ph0[8], ph1[8];
        {
            float ps0 = 0.f, ps1 = 0.f;
            if (m_run0 == -INFINITY) {
                #pragma unroll
                for (int i = 0; i < 8; ++i) ph0[i] = (_Float16)0.f;
            } else {
                #pragma unroll
                for (int i = 0; i < 8; ++i) {
                    float e = __expf(p0v[i] - m_run0);
                    ph0[i] = (_Float16)e;
                    ps0 += (float)ph0[i];          // sum ROUNDED weights (partial)
                }
            }
            if (m_run1 == -INFINITY) {
                #pragma unroll
                for (int i = 0; i < 8; ++i) ph1[i] = (_Float16)0.f;
            } else {
                #pragma unroll
                for (int i = 0; i < 8; ++i) {
                    float e = __expf(p1v[i] - m_run1);
                    ph1[i] = (_Float16)e;
                    ps1 += (float)ph1[i];
                }
            }
            l_run0 += ps0;   // per-lane partial; cross-lane reduce deferred to epilogue
            l_run1 += ps1;
        }

        // pf: K=32 B-frag under pi-permuted K-axis — pure register pack, no LDS/shuffle.
        // B-frag element j = P[pi(lg*8+j)][c=lr]; pi(lg*8+j) = (j<4)? 4lg+j : 16+4lg+j-4,
        // which is exactly ph[j]. qt's q-axis carries the same pi order (q_prep).
        f16x8 pf0 = {ph0[0], ph0[1], ph0[2], ph0[3], ph0[4], ph0[5], ph0[6], ph0[7]};
        f16x8 pf1 = {ph1[0], ph1[1], ph1[2], ph1[3], ph1[4], ph1[5], ph1[6], ph1[7]};

        // ---- PV both sets at K=32: O^T[h][c] += V^T[h][q] * P^T[q][c]; 32 MFMAs ----
        __builtin_amdgcn_s_setprio(1);
        #pragma unroll
        for (int n = 0; n < 8; ++n) {
            acc0[n] = __builtin_amdgcn_mfma_f32_16x16x32_f16(vt0[n], pf0, acc0[n], 0, 0, 0);
            acc1[n] = __builtin_amdgcn_mfma_f32_16x16x32_f16(vt0[n], pf1, acc1[n], 0, 0, 0);
        }
        #pragma unroll
        for (int n = 0; n < 8; ++n) {
            acc0[8+n] = __builtin_amdgcn_mfma_f32_16x16x32_f16(vt1[n], pf0, acc0[8+n], 0, 0, 0);
            acc1[8+n] = __builtin_amdgcn_mfma_f32_16x16x32_f16(vt1[n], pf1, acc1[8+n], 0, 0, 0);
        }
        __builtin_amdgcn_s_setprio(0);

        __syncthreads();   // all waves done with tile t; next tile's DMA drained
    }

    // ---- epilogue: reduce partial l across the 4 row-group lanes, then store ----
    l_run0 += __shfl_xor(l_run0, 16, 64);
    l_run0 += __shfl_xor(l_run0, 32, 64);
    l_run1 += __shfl_xor(l_run1, 16, 64);
    l_run1 += __shfl_xor(l_run1, 32, 64);
    float rinv0 = 1.f / l_run0;
    float rinv1 = 1.f / l_run1;
    float* orow0 = out + (size_t)(c0 + wid*16 + lr) * BH + b*HDIM;
    float* orow1 = orow0 + (size_t)64 * BH;
    #pragma unroll
    for (int n = 0; n < 16; ++n) {
        f32x4 v0 = acc0[n] * rinv0;
        f32x4 v1 = acc1[n] * rinv1;
        *reinterpret_cast<f32x4*>(orow0 + n*16 + lg*4) = v0;
        *reinterpret_cast<f32x4*>(orow1 + n*16 + lg*4) = v1;
    }
}

extern "C" void kernel_launch(void* const* d_in, const int* in_sizes, int n_in,
                              void* d_out, int out_size, void* d_ws, size_t ws_size,
                              hipStream_t stream) {
    const float* content  = (const float*)d_in[0];
    const float* question = (const float*)d_in[1];
    const int*   mask     = (const int*)d_in[2];
    float*       out      = (float*)d_out;

    unsigned char* blob = (unsigned char*)d_ws;   // 512 tiles * 32KB = 16 MB

    q_prep<<<BATCH * NQT, 256, 0, stream>>>(question, blob);
    s2s_attn<<<C_LENX / CBLK * BATCH, 256, 0, stream>>>(content, blob, mask, out);
}

// Round 21
// 72.379 us; speedup vs baseline: 2.6585x; 1.5148x over previous
//
#include <hip/hip_runtime.h>

#define C_LENX 2048
#define Q_LENX 512
#define BATCH  32
#define HDIM   256
#define BH     8192
#define CBLK   128            // 2 c-sets x 4 waves x 16 rows
#define QBLK   32
#define NQT    16
#define TILE_BYTES 32768      // qf 16K (fp16[32][256], swz) + qt 16K (V^T chunks, pi-order)
#define OFF_QT 16384

typedef __attribute__((ext_vector_type(8))) _Float16 f16x8;
typedef __attribute__((ext_vector_type(4))) float f32x4;

__device__ __forceinline__ unsigned short f2h_bits(float x) {
    union { _Float16 h; unsigned short u; } cv;
    cv.h = (_Float16)x;                     // RTNE
    return cv.u;
}

// async global->LDS, 16B per lane, wave-uniform LDS base + lane*16
__device__ __forceinline__ void stage16(const void* gsrc, void* ldst) {
    __builtin_amdgcn_global_load_lds(
        (const __attribute__((address_space(1))) unsigned int*)gsrc,
        (__attribute__((address_space(3))) unsigned int*)ldst, 16, 0, 0);
}

// ---------------- prep: fp32 Q -> fp16 blob ----------------
// qf: row q (512B); 16B chunk c at byte q*512 + 16*(c ^ (q&7))     [holds Q[q][8c..8c+7]]
// qt: chunk (h*4+g), PI-PERMUTED q-octet: { Q[4g..4g+3][h], Q[16+4g..16+4g+3][h] }
//     — matches the in-register P layout of lane group g, so PV needs no P shuffle.
__global__ __launch_bounds__(256)
void q_prep(const float* __restrict__ question, unsigned char* __restrict__ blob)
{
    __shared__ unsigned short sHf[QBLK][264];
    const int tid = threadIdx.x;
    const int b  = blockIdx.x >> 4;
    const int t  = blockIdx.x & 15;
    const float* qbase = question + (size_t)(t * QBLK) * BH + b * HDIM;
    unsigned char* tb = blob + (size_t)(b * NQT + t) * TILE_BYTES;

    #pragma unroll
    for (int i = 0; i < 8; ++i) {
        int e  = tid + i * 256;          // float4 cell 0..2047
        int qr = e >> 6;                 // 0..31
        int h4 = (e & 63) << 2;          // 0..252
        float4 x = *reinterpret_cast<const float4*>(qbase + (size_t)qr * BH + h4);
        ushort4 hv;
        hv.x = f2h_bits(x.x); hv.y = f2h_bits(x.y);
        hv.z = f2h_bits(x.z); hv.w = f2h_bits(x.w);
        *reinterpret_cast<ushort4*>(&sHf[qr][h4]) = hv;
        int c = h4 >> 3;                 // 16B chunk within row
        *reinterpret_cast<ushort4*>(tb + qr * 512 + ((c ^ (qr & 7)) << 4) + ((h4 & 7) << 1)) = hv;
    }
    __syncthreads();
    #pragma unroll
    for (int i = 0; i < 4; ++i) {
        int e  = tid + i * 256;          // chunk 0..1023
        int h  = e >> 2;                 // 0..255
        int g  = e & 3;                  // lane-group
        int q0 = g * 4;
        ushort4 a, bv;
        a.x  = sHf[q0 + 0][h];      a.y  = sHf[q0 + 1][h];
        a.z  = sHf[q0 + 2][h];      a.w  = sHf[q0 + 3][h];
        bv.x = sHf[16 + q0 + 0][h]; bv.y = sHf[16 + q0 + 1][h];
        bv.z = sHf[16 + q0 + 2][h]; bv.w = sHf[16 + q0 + 3][h];
        *reinterpret_cast<ushort4*>(tb + OFF_QT + e * 16)     = a;
        *reinterpret_cast<ushort4*>(tb + OFF_QT + e * 16 + 8) = bv;
    }
}

// ---- main: R18 structure + register-P (pi-permuted K-axis); vt read in-loop ----
__global__ __launch_bounds__(256, 2)
void s2s_attn(const float* __restrict__ content,
              const unsigned char* __restrict__ blob,
              const int*   __restrict__ qmask,
              float*       __restrict__ out)
{
    __shared__ __attribute__((aligned(16))) unsigned char sBuf[2 * TILE_BYTES];

    const int tid  = threadIdx.x;
    const int wid  = tid >> 6;
    const int lane = tid & 63;
    const int lr   = lane & 15;
    const int lg   = lane >> 4;

    // XCD-aware swizzle: 512 blocks, 64/XCD -> each XCD owns 4 complete batches
    const int lin = (blockIdx.x & 7) * 64 + (blockIdx.x >> 3);
    const int ct = lin & 15;             // 16 c-tiles per batch
    const int b  = lin >> 4;
    const int c0 = ct * CBLK;

    // prologue: DMA tile 0 into buffer 0 (32 segs of 1KB; 8 per wave)
    {
        const unsigned char* tb0 = blob + (size_t)(b * NQT) * TILE_BYTES;
        #pragma unroll
        for (int j = 0; j < 8; ++j) {
            int seg = wid * 8 + j;
            stage16(tb0 + seg * 1024 + lane * 16, sBuf + seg * 1024);
        }
    }

    // hoist mask: one ballot word per q-tile (wave-uniform -> SGPRs)
    unsigned mwv[NQT];
    #pragma unroll
    for (int t = 0; t < NQT; ++t)
        mwv[t] = (unsigned)__ballot(qmask[b * Q_LENX + t * QBLK + (lane & 31)] != 0);

    // content preload: two c-sets of 16 rows each (K=32 A/B layout: row=lr, k=lg*8)
    f16x8 chi0[8], chi1[8];
    {
        const float* cb0 = content + (size_t)(c0 + wid*16 + lr) * BH + b*HDIM + lg*8;
        const float* cb1 = cb0 + (size_t)64 * BH;
        #pragma unroll
        for (int kc = 0; kc < 8; ++kc) {
            float4 x0 = *reinterpret_cast<const float4*>(cb0 + kc*32);
            float4 x1 = *reinterpret_cast<const float4*>(cb0 + kc*32 + 4);
            float4 y0 = *reinterpret_cast<const float4*>(cb1 + kc*32);
            float4 y1 = *reinterpret_cast<const float4*>(cb1 + kc*32 + 4);
            float xs[8] = {x0.x,x0.y,x0.z,x0.w,x1.x,x1.y,x1.z,x1.w};
            float ys[8] = {y0.x,y0.y,y0.z,y0.w,y1.x,y1.y,y1.z,y1.w};
            #pragma unroll
            for (int j = 0; j < 8; ++j) {
                chi0[kc][j] = (_Float16)xs[j];
                chi1[kc][j] = (_Float16)ys[j];
            }
        }
    }

    // acc[s][n]: O^T fragment — lane holds O[c = c0 + s*64 + wid*16 + lr][h = n*16+lg*4+r]
    f32x4 acc0[16], acc1[16];
    #pragma unroll
    for (int n = 0; n < 16; ++n) {
        f32x4 z = {0.f,0.f,0.f,0.f};
        acc0[n] = z; acc1[n] = z;
    }
    float m_run0 = -INFINITY, m_run1 = -INFINITY;
    float l_run0 = 0.f, l_run1 = 0.f;   // per-lane PARTIAL sums; reduced at epilogue

    __syncthreads();           // tile 0 DMA drained + visible

    for (int t = 0; t < NQT; ++t) {
        const unsigned char* qf = sBuf + (t & 1) * TILE_BYTES;
        const unsigned char* qt = qf + OFF_QT;

        // T3 2-phase: issue next tile's DMA into the other buffer, compute, one barrier
        if (t + 1 < NQT) {
            const unsigned char* tbn = blob + (size_t)(b * NQT + t + 1) * TILE_BYTES;
            unsigned char* db = sBuf + ((t + 1) & 1) * TILE_BYTES;
            #pragma unroll
            for (int j = 0; j < 8; ++j) {
                int seg = wid * 8 + j;
                stage16(tbn + seg * 1024 + lane * 16, db + seg * 1024);
            }
        }
        const unsigned mw = mwv[t];

        // ---- QK^T both sets: shared qf reads; 4 chains (2 per set), depth 8 ----
        f32x4 zz = {0.f,0.f,0.f,0.f};
        f32x4 sA0=zz, sB0=zz, sA1=zz, sB1=zz;
        const unsigned swz = (unsigned)(lr & 7);   // (16+lr)&7 == lr&7
        __builtin_amdgcn_s_setprio(1);
        #pragma unroll
        for (int kc = 0; kc < 8; ++kc) {
            unsigned off = (unsigned)((kc*4 + lg) ^ swz) << 4;
            f16x8 qa = *reinterpret_cast<const f16x8*>(qf + lr*512 + off);
            f16x8 qb = *reinterpret_cast<const f16x8*>(qf + (16+lr)*512 + off);
            sA0 = __builtin_amdgcn_mfma_f32_16x16x32_f16(qa, chi0[kc], sA0, 0, 0, 0);
            sB0 = __builtin_amdgcn_mfma_f32_16x16x32_f16(qb, chi0[kc], sB0, 0, 0, 0);
            sA1 = __builtin_amdgcn_mfma_f32_16x16x32_f16(qa, chi1[kc], sA1, 0, 0, 0);
            sB1 = __builtin_amdgcn_mfma_f32_16x16x32_f16(qb, chi1[kc], sB1, 0, 0, 0);
        }
        __builtin_amdgcn_s_setprio(0);
        // sA*: S^T rows q=lg*4+r, col c=lr;  sB*: rows q=16+lg*4+r

        // ---- softmax both sets; uniform-mask fast path (mw is SGPR) ----
        float p0v[8], p1v[8];
        float tm0 = -INFINITY, tm1 = -INFINITY;
        if (mw == 0xffffffffu) {
            #pragma unroll
            for (int r = 0; r < 4; ++r) {
                p0v[r] = sA0[r]; p0v[4+r] = sB0[r];
                p1v[r] = sA1[r]; p1v[4+r] = sB1[r];
                tm0 = fmaxf(tm0, fmaxf(sA0[r], sB0[r]));
                tm1 = fmaxf(tm1, fmaxf(sA1[r], sB1[r]));
            }
        } else {
            #pragma unroll
            for (int r = 0; r < 4; ++r) {
                bool okA = (mw >> (lg*4 + r)) & 1u;
                bool okB = (mw >> (16 + lg*4 + r)) & 1u;
                float a0 = okA ? sA0[r] : -INFINITY;
                float b0v = okB ? sB0[r] : -INFINITY;
                float a1 = okA ? sA1[r] : -INFINITY;
                float b1v = okB ? sB1[r] : -INFINITY;
                p0v[r] = a0; p0v[4+r] = b0v;
                p1v[r] = a1; p1v[4+r] = b1v;
                tm0 = fmaxf(tm0, fmaxf(a0, b0v));
                tm1 = fmaxf(tm1, fmaxf(a1, b1v));
            }
        }
        tm0 = fmaxf(tm0, __shfl_xor(tm0, 16, 64));
        tm0 = fmaxf(tm0, __shfl_xor(tm0, 32, 64));
        tm1 = fmaxf(tm1, __shfl_xor(tm1, 16, 64));
        tm1 = fmaxf(tm1, __shfl_xor(tm1, 32, 64));

        if (__ballot((tm0 > m_run0 + 4.0f) || (tm1 > m_run1 + 4.0f))) {   // T13 defer-max
            float mn0 = fmaxf(m_run0, tm0);
            float mn1 = fmaxf(m_run1, tm1);
            float sc0 = 1.f, sc1 = 1.f;
            if (mn0 != -INFINITY) { sc0 = __expf(m_run0 - mn0); m_run0 = mn0; }
            if (mn1 != -INFINITY) { sc1 = __expf(m_run1 - mn1); m_run1 = mn1; }
            l_run0 *= sc0; l_run1 *= sc1;
            #pragma unroll
            for (int n = 0; n < 16; ++n) {
                acc0[n] *= sc0;
                acc1[n] *= sc1;
            }
        }

        // ---- exp + partial sums; P stays IN REGISTERS (pi-order == B-frag order) ----
        _Float16 ph0[8], ph1[8];
        {
            float ps0 = 0.f, ps1 = 0.f;
            if (m_run0 == -INFINITY) {
                #pragma unroll
                for (int i = 0; i < 8; ++i) ph0[i] = (_Float16)0.f;
            } else {
                #pragma unroll
                for (int i = 0; i < 8; ++i) {
                    float e = __expf(p0v[i] - m_run0);
                    ph0[i] = (_Float16)e;
                    ps0 += (float)ph0[i];          // sum ROUNDED weights (partial)
                }
            }
            if (m_run1 == -INFINITY) {
                #pragma unroll
                for (int i = 0; i < 8; ++i) ph1[i] = (_Float16)0.f;
            } else {
                #pragma unroll
                for (int i = 0; i < 8; ++i) {
                    float e = __expf(p1v[i] - m_run1);
                    ph1[i] = (_Float16)e;
                    ps1 += (float)ph1[i];
                }
            }
            l_run0 += ps0;   // per-lane partial; cross-lane reduce deferred to epilogue
            l_run1 += ps1;
        }

        // pf: K=32 B-frag under pi-permuted K-axis — pure register pack, no LDS/shuffle.
        // B-frag element j = P[pi(lg*8+j)][c=lr]; pi(lg*8+j) = (j<4)? 4lg+j : 16+4lg+j-4,
        // which is exactly ph[j]. qt's q-axis carries the same pi order (q_prep).
        f16x8 pf0 = {ph0[0], ph0[1], ph0[2], ph0[3], ph0[4], ph0[5], ph0[6], ph0[7]};
        f16x8 pf1 = {ph1[0], ph1[1], ph1[2], ph1[3], ph1[4], ph1[5], ph1[6], ph1[7]};

        // ---- PV both sets at K=32: vt read IN-LOOP (transient reg, R18-proven pressure) ----
        __builtin_amdgcn_s_setprio(1);
        #pragma unroll
        for (int n = 0; n < 16; ++n) {
            f16x8 vt = *reinterpret_cast<const f16x8*>(qt + (((n*16 + lr)*4 + lg) << 4));
            acc0[n] = __builtin_amdgcn_mfma_f32_16x16x32_f16(vt, pf0, acc0[n], 0, 0, 0);
            acc1[n] = __builtin_amdgcn_mfma_f32_16x16x32_f16(vt, pf1, acc1[n], 0, 0, 0);
        }
        __builtin_amdgcn_s_setprio(0);

        __syncthreads();   // all waves done with tile t; next tile's DMA drained
    }

    // ---- epilogue: reduce partial l across the 4 row-group lanes, then store ----
    l_run0 += __shfl_xor(l_run0, 16, 64);
    l_run0 += __shfl_xor(l_run0, 32, 64);
    l_run1 += __shfl_xor(l_run1, 16, 64);
    l_run1 += __shfl_xor(l_run1, 32, 64);
    float rinv0 = 1.f / l_run0;
    float rinv1 = 1.f / l_run1;
    float* orow0 = out + (size_t)(c0 + wid*16 + lr) * BH + b*HDIM;
    float* orow1 = orow0 + (size_t)64 * BH;
    #pragma unroll
    for (int n = 0; n < 16; ++n) {
        f32x4 v0 = acc0[n] * rinv0;
        f32x4 v1 = acc1[n] * rinv1;
        *reinterpret_cast<f32x4*>(orow0 + n*16 + lg*4) = v0;
        *reinterpret_cast<f32x4*>(orow1 + n*16 + lg*4) = v1;
    }
}

extern "C" void kernel_launch(void* const* d_in, const int* in_sizes, int n_in,
                              void* d_out, int out_size, void* d_ws, size_t ws_size,
                              hipStream_t stream) {
    const float* content  = (const float*)d_in[0];
    const float* question = (const float*)d_in[1];
    const int*   mask     = (const int*)d_in[2];
    float*       out      = (float*)d_out;

    unsigned char* blob = (unsigned char*)d_ws;   // 512 tiles * 32KB = 16 MB

    q_prep<<<BATCH * NQT, 256, 0, stream>>>(question, blob);
    s2s_attn<<<C_LENX / CBLK * BATCH, 256, 0, stream>>>(content, blob, mask, out);
}